// Round 13
// baseline (727.181 us; speedup 1.0000x reference)
//
#include <hip/hip_runtime.h>
#include <hip/hip_bf16.h>
#include <stdint.h>

#define HORIZON 12

typedef __bf16 bf16x8 __attribute__((ext_vector_type(8)));
typedef float  f32x16 __attribute__((ext_vector_type(16)));
typedef float  f32x4v __attribute__((ext_vector_type(4)));

__device__ __forceinline__ unsigned short f2bf(float f) {
  union { float f; uint32_t u; } v; v.f = f;
  return (unsigned short)((v.u + 0x7FFFu + ((v.u >> 16) & 1u)) >> 16);
}
__device__ __forceinline__ float bf2f(unsigned short s) {
  union { uint32_t u; float f; } v; v.u = ((uint32_t)s) << 16;
  return v.f;
}

__device__ __forceinline__ float sigm(float x) { return 1.0f / (1.0f + __expf(-x)); }
__device__ __forceinline__ float tanh_fast(float x) { return 1.0f - 2.0f / (__expf(2.0f * x) + 1.0f); }

#define MFMA(a, b, c) __builtin_amdgcn_mfma_f32_32x32x16_bf16(a, b, c, 0, 0, 0)

// ---------- prep: cast weights to bf16 in K-major slab layout + bias combos ----------
// Wb: matrix m in {Wih0,Whh0,Wih1,Whh1,Wlin} at m*196608 els; slab k (K16 window):
// el = m*196608 + (k*rows + r)*16 + kk  (r = output row, kk = k within window).
// Bc: [brz 2x256][bzz 2x256][bin 2x256][bhn 2x256][blin 256] f32.
__global__ void prep(const float* __restrict__ wih, const float* __restrict__ whh,
                     const float* __restrict__ wlin, const float* __restrict__ bih,
                     const float* __restrict__ bhh, const float* __restrict__ blin,
                     unsigned short* __restrict__ Wb, float* __restrict__ Bc) {
  const int stride = gridDim.x * blockDim.x;
  for (int i = blockIdx.x * blockDim.x + threadIdx.x; i < 215296; i += stride) {
    if (i < 212992) {
      const int e = i << 2;
      const float* src; int m, rel;
      if (e < 196608)      { src = wih + e;             m = 0; rel = e; }
      else if (e < 393216) { src = whh + (e - 196608);  m = 1; rel = e - 196608; }
      else if (e < 589824) { src = wih + (e - 196608);  m = 2; rel = e - 393216; }
      else if (e < 786432) { src = whh + (e - 393216);  m = 3; rel = e - 589824; }
      else                 { src = wlin + (e - 786432); m = 4; rel = e - 786432; }
      const int rows = (m < 4) ? 768 : 256;
      const int r = rel >> 8, c = rel & 255;
      const float4 v = *(const float4*)src;
      unsigned short* dst = Wb + m * 196608 + ((c >> 4) * rows + r) * 16 + (c & 15);
      dst[0] = f2bf(v.x); dst[1] = f2bf(v.y); dst[2] = f2bf(v.z); dst[3] = f2bf(v.w);
    } else {
      const int t = i - 212992;
      float v;
      if (t < 512)       { const int l = t >> 8,        d = t & 255; v = bih[l*768+d]     + bhh[l*768+d]; }
      else if (t < 1024) { const int l = (t-512) >> 8,  d = t & 255; v = bih[l*768+256+d] + bhh[l*768+256+d]; }
      else if (t < 1536) { const int l = (t-1024) >> 8, d = t & 255; v = bih[l*768+512+d]; }
      else if (t < 2048) { const int l = (t-1536) >> 8, d = t & 255; v = bhh[l*768+512+d]; }
      else               { v = blin[t - 2048]; }
      Bc[t] = v;
    }
  }
}

// ---------- persistent fused decoder ----------
// Round-13: TLP instead of ILP. 256 blocks x 1024 threads (16 waves) ->
// 4 waves/SIMD (2x r6's occupancy); latency-bound T_iter ~ L/waves halves.
// Waves = 8 dim-groups x 2 batch-halves: per-wave work shrinks so the
// 4-wave register budget (128/wave, unified) holds: acc 32 (two-phase gates,
// r12) + frags 4x2x4=32 + packed r,z 16 + A-frags 8 + ptrs/misc ~25 < 128.
// Depth-1 prefetch only (r7-r12: anything deeper spills).
// D[row=batch][col=dim]: A = x/h bf16 from LDS, B = W^T frags from global.
// C/D: col = lane&31 = dim, row = (reg&3)+8*(reg>>2)+4*(lane>>5) = batch row.
// LDS x/h: [64 rows][256 dims] bf16, granule g at slot g^(row&31) (conflict-free).
__global__ __launch_bounds__(1024) __attribute__((amdgpu_waves_per_eu(4, 4)))
void rnn_persist(
    const float* __restrict__ y0, const float* __restrict__ h0f,
    const unsigned short* __restrict__ Wb, const float* __restrict__ Bc,
    float* __restrict__ out) {
  extern __shared__ char lds[];
  char* XB = lds;            // 32 KB bf16 [64][256]
  char* H0 = lds + 32768;    // 32 KB
  char* H1 = lds + 65536;    // 32 KB

  const int tid = threadIdx.x;
  const int w   = tid >> 6;              // 0..15
  const int dg  = w & 7;                 // dim-group
  const int bh  = w >> 3;                // batch-half
  const int l   = tid & 63;
  const int l31 = l & 31;
  const int hi  = l >> 5;
  const int b0  = blockIdx.x * 64;
  const int dw  = dg * 32 + l31;         // this lane's output dim
  const int sub2 = (l31 & 7) * 2;        // byte pos of dim within its granule
  const int gdw  = dg * 4 + (l31 >> 3);  // dim-granule index of dw
  const int arow = bh * 32 + l31;        // A-frag LDS row

  f32x16 A0, A1;                         // 32-reg accumulator (reused per phase)
  uint32_t rp[8], zp[8];                 // packed bf16 r,z (16 regs)

  // ---- init XB = bf16(y0 stripe), swizzled ----
#pragma unroll
  for (int rr = 0; rr < 4; ++rr) {
    const int idx = rr * 4096 + tid * 4;
    const int row = idx >> 8, dd = idx & 255;
    const f32x4v v = __builtin_nontemporal_load(
        (const f32x4v*)(y0 + (size_t)(b0 + row) * 256 + dd));
    ushort4 o; o.x = f2bf(v.x); o.y = f2bf(v.y); o.z = f2bf(v.z); o.w = f2bf(v.w);
    *(ushort4*)(XB + row * 512 + (((dd >> 3) ^ (row & 31)) << 4) + (dd & 7) * 2) = o;
  }

  // ---- init H0/H1 = bf16(h0 stripes), swizzled ----
  auto initH = [&](const float* src, char* Hl) {
#pragma unroll
    for (int rr = 0; rr < 4; ++rr) {
      const int idx = rr * 4096 + tid * 4;
      const int row = idx >> 8, dd = idx & 255;
      const f32x4v v = __builtin_nontemporal_load(
          (const f32x4v*)(src + (size_t)(b0 + row) * 256 + dd));
      ushort4 o; o.x = f2bf(v.x); o.y = f2bf(v.y); o.z = f2bf(v.z); o.w = f2bf(v.w);
      *(ushort4*)(Hl + row * 512 + (((dd >> 3) ^ (row & 31)) << 4) + (dd & 7) * 2) = o;
    }
  };
  initH(h0f, H0);
  initH(h0f + (size_t)16384 * 256, H1);
  __syncthreads();

  const char* Wp = (const char*)Wb;

  auto zacc = [&]() {
#pragma unroll
    for (int r = 0; r < 16; ++r) { A0[r] = 0.0f; A1[r] = 0.0f; }
  };

  // Phase-A pass: 4 streams {x@Wr, x@Wz, h@Ur, h@Uz}, depth-1 prefetch.
  auto passA = [&](const char* Xs, const char* Hs, size_t mI, size_t mH) {
    const char* q0 = Wp + mI + (size_t)(0 * 256 + dw) * 32 + hi * 16;
    const char* q1 = Wp + mI + (size_t)(1 * 256 + dw) * 32 + hi * 16;
    const char* q2 = Wp + mH + (size_t)(0 * 256 + dw) * 32 + hi * 16;
    const char* q3 = Wp + mH + (size_t)(1 * 256 + dw) * 32 + hi * 16;
    bf16x8 f[2][4];
#define LOADSET4(buf)                                          \
    f[buf][0] = *(const bf16x8*)q0; q0 += 24576;               \
    f[buf][1] = *(const bf16x8*)q1; q1 += 24576;               \
    f[buf][2] = *(const bf16x8*)q2; q2 += 24576;               \
    f[buf][3] = *(const bf16x8*)q3; q3 += 24576;               \
    asm volatile("" : "+v"(q0), "+v"(q1), "+v"(q2), "+v"(q3));
    LOADSET4(0)
#pragma unroll
    for (int k = 0; k < 16; ++k) {
      if (k < 15) { LOADSET4((k + 1) & 1) }
      const int cur = k & 1;
      const int go = ((2 * k + hi) ^ l31) << 4;
      const bf16x8 aX = *(const bf16x8*)(Xs + arow * 512 + go);
      const bf16x8 aH = *(const bf16x8*)(Hs + arow * 512 + go);
      __builtin_amdgcn_s_setprio(1);
      A0 = MFMA(aX, f[cur][0], A0);
      A1 = MFMA(aX, f[cur][1], A1);
      A0 = MFMA(aH, f[cur][2], A0);
      A1 = MFMA(aH, f[cur][3], A1);
      __builtin_amdgcn_s_setprio(0);
    }
#undef LOADSET4
  };

  // Phase-B pass: 2 streams {x@Wn, h@Un}, depth-1 prefetch.
  auto passB = [&](const char* Xs, const char* Hs, size_t mI, size_t mH) {
    const char* q0 = Wp + mI + (size_t)(2 * 256 + dw) * 32 + hi * 16;
    const char* q1 = Wp + mH + (size_t)(2 * 256 + dw) * 32 + hi * 16;
    bf16x8 f[2][2];
#define LOADSET2(buf)                                          \
    f[buf][0] = *(const bf16x8*)q0; q0 += 24576;               \
    f[buf][1] = *(const bf16x8*)q1; q1 += 24576;               \
    asm volatile("" : "+v"(q0), "+v"(q1));
    LOADSET2(0)
#pragma unroll
    for (int k = 0; k < 16; ++k) {
      if (k < 15) { LOADSET2((k + 1) & 1) }
      const int cur = k & 1;
      const int go = ((2 * k + hi) ^ l31) << 4;
      const bf16x8 aX = *(const bf16x8*)(Xs + arow * 512 + go);
      const bf16x8 aH = *(const bf16x8*)(Hs + arow * 512 + go);
      __builtin_amdgcn_s_setprio(1);
      A0 = MFMA(aX, f[cur][0], A0);
      A1 = MFMA(aH, f[cur][1], A1);
      __builtin_amdgcn_s_setprio(0);
    }
#undef LOADSET2
  };

  auto passLin = [&](const char* Hs, size_t mL) {
    const char* pL = Wp + mL + (size_t)dw * 32 + hi * 16;
    bf16x8 f[2];
    f[0] = *(const bf16x8*)pL; pL += 8192;
    asm volatile("" : "+v"(pL));
#pragma unroll
    for (int k = 0; k < 16; ++k) {
      if (k < 15) {
        f[(k + 1) & 1] = *(const bf16x8*)pL; pL += 8192;
        asm volatile("" : "+v"(pL));
      }
      const int cur = k & 1;
      const int go = ((2 * k + hi) ^ l31) << 4;
      const bf16x8 a0 = *(const bf16x8*)(Hs + arow * 512 + go);
      __builtin_amdgcn_s_setprio(1);
      A0 = MFMA(a0, f[cur], A0);
      __builtin_amdgcn_s_setprio(0);
    }
  };

  // epiA: r,z = sigm(S + bias), pack bf16 pairs into rp/zp (thread-local).
  auto epiA = [&](int L) {
    const float brz = Bc[L * 256 + dw];
    const float bzz = Bc[512 + L * 256 + dw];
#pragma unroll
    for (int j = 0; j < 8; ++j) {
      const float r0 = sigm(A0[2 * j]     + brz);
      const float r1 = sigm(A0[2 * j + 1] + brz);
      const float z0 = sigm(A1[2 * j]     + bzz);
      const float z1 = sigm(A1[2 * j + 1] + bzz);
      rp[j] = (uint32_t)f2bf(r0) | ((uint32_t)f2bf(r1) << 16);
      zp[j] = (uint32_t)f2bf(z0) | ((uint32_t)f2bf(z1) << 16);
    }
  };

  // epiB: n = tanh(In + bin + r*(Hn + bhn)); h = (1-z)n + z*h_old (LDS RMW).
  auto epiB = [&](int L, char* Hl) {
    const float bin = Bc[1024 + L * 256 + dw];
    const float bhn = Bc[1536 + L * 256 + dw];
#pragma unroll
    for (int j = 0; j < 8; ++j) {
#pragma unroll
      for (int e = 0; e < 2; ++e) {
        const int reg = 2 * j + e;
        const float rr = bf2f((unsigned short)(e ? (rp[j] >> 16) : (rp[j] & 0xFFFF)));
        const float zz = bf2f((unsigned short)(e ? (zp[j] >> 16) : (zp[j] & 0xFFFF)));
        const int rl = (reg & 3) + 8 * (reg >> 2) + 4 * hi;
        unsigned short* hp =
            (unsigned short*)(Hl + (bh * 32 + rl) * 512 + ((gdw ^ rl) << 4) + sub2);
        const float hold = bf2f(*hp);
        const float nn = tanh_fast(A0[reg] + bin + rr * (A1[reg] + bhn));
        const float hv = (1.0f - zz) * nn + zz * hold;
        *hp = f2bf(hv);
      }
    }
  };

#pragma unroll 1
  for (int t = 0; t < HORIZON; ++t) {
    // ---- layer 0 ----
    zacc();
    passA(XB, H0, 0, 393216);      // S_r,S_z
    epiA(0);
    zacc();
    passB(XB, H0, 0, 393216);      // I_n,H_n
    __syncthreads();               // all waves done reading H0-old
    epiB(0, H0);
    __syncthreads();               // H0-new visible
    // ---- layer 1 ----
    zacc();
    passA(H0, H1, 786432, 1179648);
    epiA(1);
    zacc();
    passB(H0, H1, 786432, 1179648);
    __syncthreads();
    epiB(1, H1);
    __syncthreads();
    // ---- output linear ----
#pragma unroll
    for (int r = 0; r < 16; ++r) A0[r] = 0.0f;
    passLin(H1, 1572864);
    // direct epilogue: fp32 y NT-stores (128B-contiguous per 32-lane group)
    // + bf16 next-x into XB (owner-exclusive, swizzled)
    {
      const float bl = Bc[2048 + dw];
      float* og = out + ((size_t)t * 16384 + b0) * 256;
#pragma unroll
      for (int reg = 0; reg < 16; ++reg) {
        const int rl = (reg & 3) + 8 * (reg >> 2) + 4 * hi;
        const int row = bh * 32 + rl;
        const float y = A0[reg] + bl;
        __builtin_nontemporal_store(y, og + (size_t)row * 256 + dw);
        *(unsigned short*)(XB + row * 512 + ((gdw ^ rl) << 4) + sub2) = f2bf(y);
      }
    }
    __syncthreads();               // XB visible for next t
  }
}

// ---------- launch ----------
extern "C" void kernel_launch(void* const* d_in, const int* in_sizes, int n_in,
                              void* d_out, int out_size, void* d_ws, size_t ws_size,
                              hipStream_t stream) {
  (void)in_sizes; (void)n_in; (void)out_size; (void)ws_size;
  const float* y0   = (const float*)d_in[0];
  const float* h0   = (const float*)d_in[1];
  const float* wih  = (const float*)d_in[2];
  const float* whh  = (const float*)d_in[3];
  const float* bih  = (const float*)d_in[4];
  const float* bhh  = (const float*)d_in[5];
  const float* wlin = (const float*)d_in[6];
  const float* blin = (const float*)d_in[7];
  float* out = (float*)d_out;

  unsigned short* Wb = (unsigned short*)d_ws;            // 851968 bf16 els
  float* Bc = (float*)((char*)d_ws + 1703936);           // 2304 f32

  static bool attr_done = false;
  if (!attr_done) {
    (void)hipFuncSetAttribute((const void*)rnn_persist,
                              hipFuncAttributeMaxDynamicSharedMemorySize, 98304);
    attr_done = true;
  }

  prep<<<512, 256, 0, stream>>>(wih, whh, wlin, bih, bhh, blin, Wb, Bc);
  rnn_persist<<<256, 1024, 98304, stream>>>(y0, h0, Wb, Bc, out);
}